// Round 4
// baseline (1693.816 us; speedup 1.0000x reference)
//
#include <hip/hip_runtime.h>
#include <cstddef>

#define NPTS 500000
#define DF 64
#define NC 10000
#define BN_EPS 1e-5f

#define TPB 256
#define PTILE 64
#define NTILES ((NPTS + PTILE - 1) / PTILE)  // 7813
#define GBLK 1024  // Q / K+M grids: 4 blocks/CU x 256 CU
#define VBLK 768   // V grid: 3 blocks/CU (heavier registers)

// ---- order-preserving float<->uint encoding (for atomic max on floats) ----
__device__ __forceinline__ unsigned f2o(float f) {
  unsigned u = __float_as_uint(f);
  return (u & 0x80000000u) ? ~u : (u | 0x80000000u);
}
__device__ __forceinline__ float o2f(unsigned u) {
  return __uint_as_float((u & 0x80000000u) ? (u ^ 0x80000000u) : ~u);
}

// async global->LDS, 16B per lane. LDS dest is wave-uniform base + lane*16.
__device__ __forceinline__ void gload16(const float* g, float* l) {
  __builtin_amdgcn_global_load_lds(
      (const __attribute__((address_space(1))) void*)g,
      (__attribute__((address_space(3))) void*)l, 16, 0, 0);
}

// Stage one 64-point x tile (16 KB) into a linear LDS buffer.
// PRE-SWIZZLED source: LDS 16B-slot (p, jb) receives x[p][(jb ^ (p&15))*4..].
// Compute-side (lane-owns-row) reads chunk j4 of row p at slot j4 ^ (p&15):
// at fixed j4 the 64 lanes hit 16 distinct 16B chunks x 4 rows = uniform
// 8 touches/bank -> ds_read_b128 floor throughput (dest stays linear, rule 21).
__device__ __forceinline__ void stage_tile(float* xsbuf, const float* x,
                                           int pbase, int wave, int lane) {
#pragma unroll
  for (int i = 0; i < 4; ++i) {
    const int chunk = wave * 4 + i;       // 0..15, wave-uniform
    const int slot = chunk * 64 + lane;   // 16B slot id 0..1023
    const int p = slot >> 4;              // local point 0..63
    const int jb = slot & 15;             // 16B column block
    int gp = pbase + p;
    if (gp >= NPTS) gp = NPTS - 1;        // tail: safe garbage row
    const int jsrc = jb ^ (p & 15);
    gload16(x + (size_t)gp * DF + jsrc * 4, xsbuf + chunk * 256);
  }
}

// ws layout (float/uint units):
// 0        : q_u     [NC*DF]   sortable-uint segment max of Q projections
// 640000   : mmax_u  [NC]      sortable-uint segment max of M
// 650000   : denom   [NC]      segment sum of exp
// 660000   : sums    [2*DF]    [sum h | sum h^2]
// 660128   : scale   [DF]
// 660192   : shift   [DF]
// 660256   : Mv      [NPTS]

// ---------------------------------------------------------------------------
// Scalar-W GEMM passes. Wave w owns features f0=16w..f0+15 (wave-uniform ->
// W and bias stream through s_load / SMEM pipe, zero LDS cost). Lane owns one
// point p = pbase+lane: 16 ds_read_b128 per thread-tile (vs 128 in the
// LDS-broadcast family -> LDS pipe 118us -> ~10us per pass).
// MODE 0 (Q): segment-max into q_u (read-filtered atomics).
// MODE 1 (K+M): K proj in regs, M = dot(q[c],k) via cross-wave LDS reduce,
//               Mv store + filtered atomicMax mmax_u.  k never hits HBM.
// MODE 2 (V): h = attn*v -> out (raw h), BN sums accumulated.
// ---------------------------------------------------------------------------
template <int MODE>
__launch_bounds__(TPB, MODE == 2 ? 3 : 4)
__global__ void pass_kernel(
    const float* __restrict__ x, const int* __restrict__ cluster,
    const float* __restrict__ W, const float* __restrict__ bias,
    unsigned* __restrict__ q_u, unsigned* __restrict__ mmax_u,
    const float* __restrict__ denom, float* __restrict__ Mv,
    float* __restrict__ sums, float* __restrict__ out) {
  __shared__ float xs[2][PTILE * DF];  // double-buffered x tiles, 2 x 16 KB
  __shared__ float mred[TPB];          // MODE 1 cross-wave dot reduce

  const int tid = threadIdx.x;
  const int lane = tid & 63;
  const int wave = tid >> 6;
  const int uw = __builtin_amdgcn_readfirstlane(wave);  // force SGPR
  const int f0 = uw * 16;                               // wave's features
  const int psw = (lane & 15) << 2;                     // read-side swizzle
  const int grid = (MODE == 2) ? VBLK : GBLK;

  float s1[16], s2[16];
  if (MODE == 2) {
#pragma unroll
    for (int f = 0; f < 16; ++f) { s1[f] = 0.f; s2[f] = 0.f; }
  }

  // ---- prologue: stage tile t0 into buf0, drain, barrier ----
  int t = blockIdx.x;
  stage_tile(xs[0], x, t * PTILE, wave, lane);
  asm volatile("s_waitcnt vmcnt(0) lgkmcnt(0)" ::: "memory");
  __builtin_amdgcn_s_barrier();
  asm volatile("" ::: "memory");

  int cur = 0;
  for (; t < NTILES; t += grid) {
    const int pbase = t * PTILE;
    // prefetch next tile (in flight under the whole GEMM)
    stage_tile(xs[cur ^ 1], x, (t + grid) * PTILE, wave, lane);
    const int p = pbase + lane;
    const bool valid = p < NPTS;
    const int cc = cluster[valid ? p : NPTS - 1];
    asm volatile("" ::: "memory");

    // ---- GEMM: acc[f] = x[p] . W[f0+f] + b ; W via scalar loads ----
    float acc[16];
#pragma unroll
    for (int f = 0; f < 16; ++f) acc[f] = bias[f0 + f];  // uniform -> s_load
    const float* xrow = &xs[cur][lane * DF];
#pragma unroll
    for (int j4 = 0; j4 < 16; ++j4) {
      const float4 xv = *(const float4*)(xrow + (((j4 << 2) ^ psw)));
#pragma unroll
      for (int f = 0; f < 16; ++f) {
        const float* wr = W + (size_t)(f0 + f) * DF + j4 * 4;  // uniform
        acc[f] = fmaf(xv.x, wr[0], acc[f]);
        acc[f] = fmaf(xv.y, wr[1], acc[f]);
        acc[f] = fmaf(xv.z, wr[2], acc[f]);
        acc[f] = fmaf(xv.w, wr[3], acc[f]);
      }
    }

    // ---- mode-specific epilogue (lane owns point p, feats f0..f0+15) ----
    if (MODE == 0) {
      if (valid) {
        unsigned* dst = q_u + (size_t)cc * DF + f0;
        // monotone q_u: stale read only under-reports -> filter is race-safe
#pragma unroll
        for (int i = 0; i < 4; ++i) {
          const uint4 cq = *(const uint4*)(dst + i * 4);
          const unsigned e0 = f2o(acc[i * 4 + 0]);
          const unsigned e1 = f2o(acc[i * 4 + 1]);
          const unsigned e2 = f2o(acc[i * 4 + 2]);
          const unsigned e3 = f2o(acc[i * 4 + 3]);
          if (e0 > cq.x) atomicMax(dst + i * 4 + 0, e0);
          if (e1 > cq.y) atomicMax(dst + i * 4 + 1, e1);
          if (e2 > cq.z) atomicMax(dst + i * 4 + 2, e2);
          if (e3 > cq.w) atomicMax(dst + i * 4 + 3, e3);
        }
      }
    } else if (MODE == 1) {
      float partial = 0.f;
      if (valid) {
        const unsigned* qp = q_u + (size_t)cc * DF + f0;
#pragma unroll
        for (int i = 0; i < 4; ++i) {
          const uint4 qu = *(const uint4*)(qp + i * 4);
          partial += o2f(qu.x) * acc[i * 4 + 0] + o2f(qu.y) * acc[i * 4 + 1] +
                     o2f(qu.z) * acc[i * 4 + 2] + o2f(qu.w) * acc[i * 4 + 3];
        }
      }
      mred[wave * 64 + lane] = partial;
      asm volatile("s_waitcnt lgkmcnt(0)" ::: "memory");
      __builtin_amdgcn_s_barrier();
      asm volatile("" ::: "memory");
      if (uw == 0 && valid) {
        const float M =
            mred[lane] + mred[64 + lane] + mred[128 + lane] + mred[192 + lane];
        Mv[p] = M;
        const unsigned e = f2o(M);
        unsigned* mm = mmax_u + cc;
        if (e > *mm) atomicMax(mm, e);
      }
      asm volatile("" ::: "memory");
    } else {  // MODE 2
      if (valid) {
        const float attn = __expf(Mv[p] - o2f(mmax_u[cc])) / denom[cc];
        float* op = out + (size_t)p * DF + f0;
#pragma unroll
        for (int i = 0; i < 4; ++i) {
          float4 h;
          h.x = attn * acc[i * 4 + 0];
          h.y = attn * acc[i * 4 + 1];
          h.z = attn * acc[i * 4 + 2];
          h.w = attn * acc[i * 4 + 3];
          s1[i * 4 + 0] += h.x; s1[i * 4 + 1] += h.y;
          s1[i * 4 + 2] += h.z; s1[i * 4 + 3] += h.w;
          s2[i * 4 + 0] += h.x * h.x; s2[i * 4 + 1] += h.y * h.y;
          s2[i * 4 + 2] += h.z * h.z; s2[i * 4 + 3] += h.w * h.w;
          *(float4*)(op + i * 4) = h;  // raw h; bn+relu later
        }
      }
    }

    // ---- pipeline turn: drain prefetch (landed during GEMM), one barrier
    asm volatile("s_waitcnt vmcnt(0)" ::: "memory");
    __builtin_amdgcn_s_barrier();
    asm volatile("" ::: "memory");
    cur ^= 1;
  }

  if constexpr (MODE == 2) {
    // per-feature reduce over the 64 lanes (points); one atomic per feat/wave
#pragma unroll
    for (int f = 0; f < 16; ++f) {
      float a = s1[f], b = s2[f];
#pragma unroll
      for (int m = 1; m < 64; m <<= 1) {
        a += __shfl_xor(a, m, 64);
        b += __shfl_xor(b, m, 64);
      }
      if (lane == 0) {
        atomicAdd(sums + f0 + f, a);
        atomicAdd(sums + DF + f0 + f, b);
      }
    }
  }
}

__global__ void denom_kernel(const float* __restrict__ Mv,
                             const int* __restrict__ cluster,
                             const unsigned* __restrict__ mmax_u,
                             float* __restrict__ denom) {
  int i = blockIdx.x * blockDim.x + threadIdx.x;
  if (i < NPTS) {
    int c = cluster[i];
    atomicAdd(denom + c, __expf(Mv[i] - o2f(mmax_u[c])));
  }
}

__global__ void finalize_kernel(const float* __restrict__ sums,
                                const float* __restrict__ gamma,
                                const float* __restrict__ beta,
                                float* __restrict__ scale,
                                float* __restrict__ shift) {
  int d = threadIdx.x;
  float mean = sums[d] * (1.0f / NPTS);
  float var = sums[DF + d] * (1.0f / NPTS) - mean * mean;
  float s = gamma[d] * rsqrtf(var + BN_EPS);
  scale[d] = s;
  shift[d] = fmaf(-mean, s, beta[d]);
}

// out = relu(out*scale + shift), pure streaming, in place.
#define BNBLK 2048
__global__ void bnrelu_kernel(float* __restrict__ out,
                              const float* __restrict__ scale,
                              const float* __restrict__ shift) {
  const int g = blockIdx.x * TPB + threadIdx.x;  // 524288 threads
  const int c = g & 15;                          // column float4-chunk
  const float4 sc = *(const float4*)(scale + c * 4);
  const float4 sh = *(const float4*)(shift + c * 4);
  const int rstride = (BNBLK * TPB) >> 4;        // 32768 rows per step
  for (int r = g >> 4; r < NPTS; r += rstride) {
    float4* p = (float4*)(out + (size_t)r * DF) + c;
    float4 h = *p;
    h.x = fmaxf(fmaf(h.x, sc.x, sh.x), 0.f);
    h.y = fmaxf(fmaf(h.y, sc.y, sh.y), 0.f);
    h.z = fmaxf(fmaf(h.z, sc.z, sh.z), 0.f);
    h.w = fmaxf(fmaf(h.w, sc.w, sh.w), 0.f);
    *p = h;
  }
}

extern "C" void kernel_launch(void* const* d_in, const int* in_sizes, int n_in,
                              void* d_out, int out_size, void* d_ws,
                              size_t ws_size, hipStream_t stream) {
  const float* x = (const float*)d_in[1];
  const int* cluster = (const int*)d_in[2];
  const float* Wv = (const float*)d_in[3];
  const float* bv = (const float*)d_in[4];
  const float* Wk = (const float*)d_in[5];
  const float* bk = (const float*)d_in[6];
  const float* Wq = (const float*)d_in[7];
  const float* bq = (const float*)d_in[8];
  const float* gamma = (const float*)d_in[9];
  const float* beta = (const float*)d_in[10];
  float* out = (float*)d_out;

  float* ws = (float*)d_ws;
  unsigned* q_u = (unsigned*)ws;
  unsigned* mmax_u = (unsigned*)(ws + 640000);
  float* denom = ws + 650000;
  float* sums = ws + 660000;
  float* scale = ws + 660128;
  float* shift = ws + 660192;
  float* Mv = ws + 660256;

  // zero q_u / mmax_u / denom / sums (0u == sortable "-inf" sentinel)
  hipMemsetAsync(d_ws, 0, 660256 * sizeof(float), stream);

  // 1) Q projection -> q_u segment-max
  pass_kernel<0><<<GBLK, TPB, 0, stream>>>(x, cluster, Wq, bq, q_u, mmax_u,
                                           denom, Mv, sums, out);
  // 2) K projection + M = q[c].k + mmax segment-max (k stays in registers)
  pass_kernel<1><<<GBLK, TPB, 0, stream>>>(x, cluster, Wk, bk, q_u, mmax_u,
                                           denom, Mv, sums, out);
  // 3) softmax denominators
  denom_kernel<<<(NPTS + 255) / 256, 256, 0, stream>>>(Mv, cluster, mmax_u,
                                                       denom);
  // 4) V projection + attn weighting + BN stats, raw h -> out
  pass_kernel<2><<<VBLK, TPB, 0, stream>>>(x, cluster, Wv, bv, q_u, mmax_u,
                                           denom, Mv, sums, out);
  // 5) BN scale/shift
  finalize_kernel<<<1, 64, 0, stream>>>(sums, gamma, beta, scale, shift);
  // 6) streaming bn+relu in place
  bnrelu_kernel<<<BNBLK, TPB, 0, stream>>>(out, scale, shift);
}

// Round 6
// 582.034 us; speedup vs baseline: 2.9102x; 2.9102x over previous
//
#include <hip/hip_runtime.h>
#include <cstddef>

#define NPTS 500000
#define DF 64
#define NC 10000
#define BN_EPS 1e-5f

#define TPB 256
#define PT 128                              // points per tile
#define NT ((NPTS + PT - 1) / PT)           // 3907 tiles
#define QKBLK 512                           // 2 blocks/CU (64 KB LDS)
#define VBLK 512                            // 2 blocks/CU (80 KB LDS)

// ---- order-preserving float<->uint encoding (for atomic max on floats) ----
__device__ __forceinline__ unsigned f2o(float f) {
  unsigned u = __float_as_uint(f);
  return (u & 0x80000000u) ? ~u : (u | 0x80000000u);
}
__device__ __forceinline__ float o2f(unsigned u) {
  return __uint_as_float((u & 0x80000000u) ? (u ^ 0x80000000u) : ~u);
}

// async global->LDS, 16B per lane. LDS dest is wave-uniform base + lane*16.
__device__ __forceinline__ void gload16(const float* g, float* l) {
  __builtin_amdgcn_global_load_lds(
      (const __attribute__((address_space(1))) void*)g,
      (__attribute__((address_space(3))) void*)l, 16, 0, 0);
}

// Stage one 128-point x tile (32 KB) into a linear LDS buffer.
// PRE-SWIZZLED source: LDS 16B-slot (p, jb) receives x[p][(jb ^ ((p>>3)&3))*4].
// Read side: thread (fg,pg) reads row r=pg*8+pp at chunk j4 ^ (pg&3) =
// j4 ^ ((r>>3)&3): the 4 pg-rows a wave touches per step map to 4 distinct
// 16B chunks (16-lane broadcast each) -> conflict-free; dest linear (rule 21).
__device__ __forceinline__ void stage_tile128(float* xsbuf, const float* x,
                                              int pbase, int wave, int lane) {
#pragma unroll
  for (int i = 0; i < 8; ++i) {
    const int chunk = wave * 8 + i;       // 0..31, wave-uniform
    const int slot = chunk * 64 + lane;   // 16B slot id 0..2047
    const int p = slot >> 4;              // local point 0..127
    const int jb = slot & 15;             // 16B column block
    int gp = pbase + p;
    if (gp >= NPTS) gp = NPTS - 1;        // tail: safe garbage row
    const int jsrc = jb ^ ((p >> 3) & 3);
    gload16(x + (size_t)gp * DF + jsrc * 4, xsbuf + chunk * 256);
  }
}

// ws layout (float/uint units):
// 0        : q_u     [NC*DF]   sortable-uint segment max of Q projections
// 640000   : mmax_u  [NC]      sortable-uint segment max of M
// 650000   : denom   [NC]      segment sum of exp
// 660000   : sums    [2*DF]    [sum h | sum h^2]
// 660128   : scale   [DF]
// 660192   : shift   [DF]
// 660256   : Mv      [NPTS]
// k rows are staged in d_out (dead until the V pass overwrites it with h).

// ---------------------------------------------------------------------------
// Fused Q+K projection, P=8: one x staging, two GEMMs, 32 LDS-reads/point
// (vs 48 at P=4). Thread (fg=tid&15, pg=tid>>4) owns features f0..f0+3 of
// points pg*8..pg*8+7.  Q -> filtered atomicMax q_u ; K -> rows to kout.
// ---------------------------------------------------------------------------
__launch_bounds__(TPB, 2)
__global__ void qk_kernel(const float* __restrict__ x,
                          const int* __restrict__ cluster,
                          const float* __restrict__ Wq,
                          const float* __restrict__ bq,
                          const float* __restrict__ Wk,
                          const float* __restrict__ bk,
                          unsigned* __restrict__ q_u,
                          float* __restrict__ kout) {
  __shared__ float Wt2[DF * 128];  // 32 KB: Wt2[j][f] Q at f, K at f+64
  __shared__ float xs[PT * DF];    // 32 KB x tile

  const int tid = threadIdx.x;
  const int lane = tid & 63;
  const int wave = tid >> 6;
  const int fg = tid & 15;
  const int pg = tid >> 4;
  const int f0 = fg * 4;

  // ---- stage both W's transposed (once per block) ----
  {
    const int f = tid & 63;
    const int jb = (tid >> 6) * 16;
#pragma unroll
    for (int i = 0; i < 4; ++i) {
      float4 a = *(const float4*)(Wq + f * DF + jb + i * 4);
      Wt2[(jb + i * 4 + 0) * 128 + f] = a.x;
      Wt2[(jb + i * 4 + 1) * 128 + f] = a.y;
      Wt2[(jb + i * 4 + 2) * 128 + f] = a.z;
      Wt2[(jb + i * 4 + 3) * 128 + f] = a.w;
      float4 b = *(const float4*)(Wk + f * DF + jb + i * 4);
      Wt2[(jb + i * 4 + 0) * 128 + 64 + f] = b.x;
      Wt2[(jb + i * 4 + 1) * 128 + 64 + f] = b.y;
      Wt2[(jb + i * 4 + 2) * 128 + 64 + f] = b.z;
      Wt2[(jb + i * 4 + 3) * 128 + 64 + f] = b.w;
    }
  }
  const float4 bq4 = *(const float4*)(bq + f0);
  const float4 bk4 = *(const float4*)(bk + f0);

  for (int t = blockIdx.x; t < NT; t += QKBLK) {
    const int pbase = t * PT;
    __syncthreads();  // previous tile's readers done (covers Wt2 on iter 0)
    stage_tile128(xs, x, pbase, wave, lane);
    // cluster ids for this thread's 8 points
    int c8[8];
    {
      const int cb = pbase + pg * 8;
      if (cb + 7 < NPTS) {
        const int4 a = *(const int4*)(cluster + cb);
        const int4 b = *(const int4*)(cluster + cb + 4);
        c8[0] = a.x; c8[1] = a.y; c8[2] = a.z; c8[3] = a.w;
        c8[4] = b.x; c8[5] = b.y; c8[6] = b.z; c8[7] = b.w;
      } else {
#pragma unroll
        for (int pp = 0; pp < 8; ++pp)
          c8[pp] = cluster[cb + pp < NPTS ? cb + pp : NPTS - 1];
      }
    }
    asm volatile("s_waitcnt vmcnt(0) lgkmcnt(0)" ::: "memory");
    __syncthreads();

    // ---- dual GEMM, P=8 ----
    float4 accQ[8], accK[8];
#pragma unroll
    for (int pp = 0; pp < 8; ++pp) { accQ[pp] = bq4; accK[pp] = bk4; }
#pragma unroll 4
    for (int j4 = 0; j4 < 16; ++j4) {
      float4 wq[4], wk[4];
#pragma unroll
      for (int e = 0; e < 4; ++e) {
        wq[e] = *(const float4*)(Wt2 + (j4 * 4 + e) * 128 + f0);
        wk[e] = *(const float4*)(Wt2 + (j4 * 4 + e) * 128 + 64 + f0);
      }
      const int xoff = ((j4 ^ (pg & 3)) << 2);
#pragma unroll
      for (int pp = 0; pp < 8; ++pp) {
        const float4 xv = *(const float4*)(xs + (pg * 8 + pp) * DF + xoff);
        accQ[pp].x = fmaf(xv.x, wq[0].x, accQ[pp].x);
        accQ[pp].y = fmaf(xv.x, wq[0].y, accQ[pp].y);
        accQ[pp].z = fmaf(xv.x, wq[0].z, accQ[pp].z);
        accQ[pp].w = fmaf(xv.x, wq[0].w, accQ[pp].w);
        accQ[pp].x = fmaf(xv.y, wq[1].x, accQ[pp].x);
        accQ[pp].y = fmaf(xv.y, wq[1].y, accQ[pp].y);
        accQ[pp].z = fmaf(xv.y, wq[1].z, accQ[pp].z);
        accQ[pp].w = fmaf(xv.y, wq[1].w, accQ[pp].w);
        accQ[pp].x = fmaf(xv.z, wq[2].x, accQ[pp].x);
        accQ[pp].y = fmaf(xv.z, wq[2].y, accQ[pp].y);
        accQ[pp].z = fmaf(xv.z, wq[2].z, accQ[pp].z);
        accQ[pp].w = fmaf(xv.z, wq[2].w, accQ[pp].w);
        accQ[pp].x = fmaf(xv.w, wq[3].x, accQ[pp].x);
        accQ[pp].y = fmaf(xv.w, wq[3].y, accQ[pp].y);
        accQ[pp].z = fmaf(xv.w, wq[3].z, accQ[pp].z);
        accQ[pp].w = fmaf(xv.w, wq[3].w, accQ[pp].w);
        accK[pp].x = fmaf(xv.x, wk[0].x, accK[pp].x);
        accK[pp].y = fmaf(xv.x, wk[0].y, accK[pp].y);
        accK[pp].z = fmaf(xv.x, wk[0].z, accK[pp].z);
        accK[pp].w = fmaf(xv.x, wk[0].w, accK[pp].w);
        accK[pp].x = fmaf(xv.y, wk[1].x, accK[pp].x);
        accK[pp].y = fmaf(xv.y, wk[1].y, accK[pp].y);
        accK[pp].z = fmaf(xv.y, wk[1].z, accK[pp].z);
        accK[pp].w = fmaf(xv.y, wk[1].w, accK[pp].w);
        accK[pp].x = fmaf(xv.z, wk[2].x, accK[pp].x);
        accK[pp].y = fmaf(xv.z, wk[2].y, accK[pp].y);
        accK[pp].z = fmaf(xv.z, wk[2].z, accK[pp].z);
        accK[pp].w = fmaf(xv.z, wk[2].w, accK[pp].w);
        accK[pp].x = fmaf(xv.w, wk[3].x, accK[pp].x);
        accK[pp].y = fmaf(xv.w, wk[3].y, accK[pp].y);
        accK[pp].z = fmaf(xv.w, wk[3].z, accK[pp].z);
        accK[pp].w = fmaf(xv.w, wk[3].w, accK[pp].w);
      }
    }

    // ---- epilogue: Q segment-max + K row store ----
#pragma unroll
    for (int pp = 0; pp < 8; ++pp) {
      const int p = pbase + pg * 8 + pp;
      if (p < NPTS) {
        const int cc = c8[pp];
        unsigned* dst = q_u + (size_t)cc * DF + f0;
        // monotone q_u: stale read only under-reports -> filter is race-safe
        const uint4 curq = *(const uint4*)dst;
        const unsigned ex = f2o(accQ[pp].x);
        const unsigned ey = f2o(accQ[pp].y);
        const unsigned ez = f2o(accQ[pp].z);
        const unsigned ew = f2o(accQ[pp].w);
        if (ex > curq.x) atomicMax(dst + 0, ex);
        if (ey > curq.y) atomicMax(dst + 1, ey);
        if (ez > curq.z) atomicMax(dst + 2, ez);
        if (ew > curq.w) atomicMax(dst + 3, ew);
        *(float4*)(kout + (size_t)p * DF + f0) = accK[pp];
      }
    }
  }
}

// ---------------------------------------------------------------------------
// M = dot(q[cluster[p]], k[p]) ; Mv[p] = M ; segment-max into mmax_u.
// fg/pg layout: coalesced k rows, q_u row gather covered by 16 fg lanes.
// ---------------------------------------------------------------------------
__global__ void mdot_kernel(const float* __restrict__ k,
                            const int* __restrict__ cluster,
                            const unsigned* __restrict__ q_u,
                            float* __restrict__ Mv,
                            unsigned* __restrict__ mmax_u) {
  const int tid = threadIdx.x;
  const int fg = tid & 15;
  const int pg = tid >> 4;
  const int f0 = fg * 4;
  const int pbase = blockIdx.x * 64;
#pragma unroll
  for (int pp = 0; pp < 4; ++pp) {
    const int p = pbase + pg * 4 + pp;
    float partial = 0.f;
    int cc = 0;
    if (p < NPTS) {
      cc = cluster[p];
      const float4 kv = *(const float4*)(k + (size_t)p * DF + f0);
      const uint4 qu = *(const uint4*)(q_u + (size_t)cc * DF + f0);
      partial = o2f(qu.x) * kv.x + o2f(qu.y) * kv.y + o2f(qu.z) * kv.z +
                o2f(qu.w) * kv.w;
    }
    partial += __shfl_xor(partial, 1, 64);
    partial += __shfl_xor(partial, 2, 64);
    partial += __shfl_xor(partial, 4, 64);
    partial += __shfl_xor(partial, 8, 64);
    if (fg == 0 && p < NPTS) {
      Mv[p] = partial;
      const unsigned e = f2o(partial);
      unsigned* mm = mmax_u + cc;
      if (e > *mm) atomicMax(mm, e);
    }
  }
}

__global__ void denom_kernel(const float* __restrict__ Mv,
                             const int* __restrict__ cluster,
                             const unsigned* __restrict__ mmax_u,
                             float* __restrict__ denom) {
  int i = blockIdx.x * blockDim.x + threadIdx.x;
  if (i < NPTS) {
    int c = cluster[i];
    atomicAdd(denom + c, __expf(Mv[i] - o2f(mmax_u[c])));
  }
}

// ---------------------------------------------------------------------------
// V projection, P=8, double-buffered staging: h = attn*v -> out, BN sums.
// ---------------------------------------------------------------------------
__launch_bounds__(TPB, 2)
__global__ void v_kernel(const float* __restrict__ x,
                         const int* __restrict__ cluster,
                         const float* __restrict__ Wv,
                         const float* __restrict__ bv,
                         const unsigned* __restrict__ mmax_u,
                         const float* __restrict__ denom,
                         const float* __restrict__ Mv,
                         float* __restrict__ sums,
                         float* __restrict__ out) {
  __shared__ float Wt[DF * DF];     // 16 KB: Wt[j][f]
  __shared__ float xs[2][PT * DF];  // 2 x 32 KB double-buffered x tiles

  const int tid = threadIdx.x;
  const int lane = tid & 63;
  const int wave = tid >> 6;
  const int fg = tid & 15;
  const int pg = tid >> 4;
  const int f0 = fg * 4;

  {
    const int f = tid & 63;
    const int jb = (tid >> 6) * 16;
#pragma unroll
    for (int i = 0; i < 4; ++i) {
      float4 wr = *(const float4*)(Wv + f * DF + jb + i * 4);
      Wt[(jb + i * 4 + 0) * DF + f] = wr.x;
      Wt[(jb + i * 4 + 1) * DF + f] = wr.y;
      Wt[(jb + i * 4 + 2) * DF + f] = wr.z;
      Wt[(jb + i * 4 + 3) * DF + f] = wr.w;
    }
  }
  const float4 bv4 = *(const float4*)(bv + f0);
  float4 s1 = make_float4(0.f, 0.f, 0.f, 0.f);
  float4 s2 = make_float4(0.f, 0.f, 0.f, 0.f);

  int t = blockIdx.x;
  stage_tile128(xs[0], x, t * PT, wave, lane);
  asm volatile("s_waitcnt vmcnt(0) lgkmcnt(0)" ::: "memory");
  __builtin_amdgcn_s_barrier();
  asm volatile("" ::: "memory");

  int cur = 0;
  for (; t < NT; t += VBLK) {
    const int pbase = t * PT;
    stage_tile128(xs[cur ^ 1], x, (t + VBLK) * PT, wave, lane);
    int c8[8];
    {
      const int cb = pbase + pg * 8;
      if (cb + 7 < NPTS) {
        const int4 a = *(const int4*)(cluster + cb);
        const int4 b = *(const int4*)(cluster + cb + 4);
        c8[0] = a.x; c8[1] = a.y; c8[2] = a.z; c8[3] = a.w;
        c8[4] = b.x; c8[5] = b.y; c8[6] = b.z; c8[7] = b.w;
      } else {
#pragma unroll
        for (int pp = 0; pp < 8; ++pp)
          c8[pp] = cluster[cb + pp < NPTS ? cb + pp : NPTS - 1];
      }
    }
    asm volatile("" ::: "memory");

    float4 acc[8];
#pragma unroll
    for (int pp = 0; pp < 8; ++pp) acc[pp] = bv4;
#pragma unroll 4
    for (int j4 = 0; j4 < 16; ++j4) {
      float4 wv[4];
#pragma unroll
      for (int e = 0; e < 4; ++e)
        wv[e] = *(const float4*)(Wt + (j4 * 4 + e) * DF + f0);
      const int xoff = ((j4 ^ (pg & 3)) << 2);
#pragma unroll
      for (int pp = 0; pp < 8; ++pp) {
        const float4 xv =
            *(const float4*)(&xs[cur][(pg * 8 + pp) * DF + xoff]);
        acc[pp].x = fmaf(xv.x, wv[0].x, acc[pp].x);
        acc[pp].y = fmaf(xv.x, wv[0].y, acc[pp].y);
        acc[pp].z = fmaf(xv.x, wv[0].z, acc[pp].z);
        acc[pp].w = fmaf(xv.x, wv[0].w, acc[pp].w);
        acc[pp].x = fmaf(xv.y, wv[1].x, acc[pp].x);
        acc[pp].y = fmaf(xv.y, wv[1].y, acc[pp].y);
        acc[pp].z = fmaf(xv.y, wv[1].z, acc[pp].z);
        acc[pp].w = fmaf(xv.y, wv[1].w, acc[pp].w);
        acc[pp].x = fmaf(xv.z, wv[2].x, acc[pp].x);
        acc[pp].y = fmaf(xv.z, wv[2].y, acc[pp].y);
        acc[pp].z = fmaf(xv.z, wv[2].z, acc[pp].z);
        acc[pp].w = fmaf(xv.z, wv[2].w, acc[pp].w);
        acc[pp].x = fmaf(xv.w, wv[3].x, acc[pp].x);
        acc[pp].y = fmaf(xv.w, wv[3].y, acc[pp].y);
        acc[pp].z = fmaf(xv.w, wv[3].z, acc[pp].z);
        acc[pp].w = fmaf(xv.w, wv[3].w, acc[pp].w);
      }
    }

#pragma unroll
    for (int pp = 0; pp < 8; ++pp) {
      const int p = pbase + pg * 8 + pp;
      if (p < NPTS) {
        const int cc = c8[pp];
        const float attn = __expf(Mv[p] - o2f(mmax_u[cc])) / denom[cc];
        float4 h;
        h.x = attn * acc[pp].x;
        h.y = attn * acc[pp].y;
        h.z = attn * acc[pp].z;
        h.w = attn * acc[pp].w;
        s1.x += h.x; s1.y += h.y; s1.z += h.z; s1.w += h.w;
        s2.x += h.x * h.x; s2.y += h.y * h.y;
        s2.z += h.z * h.z; s2.w += h.w * h.w;
        *(float4*)(out + (size_t)p * DF + f0) = h;  // raw h; bn+relu later
      }
    }

    asm volatile("s_waitcnt vmcnt(0)" ::: "memory");
    __builtin_amdgcn_s_barrier();
    asm volatile("" ::: "memory");
    cur ^= 1;
  }

  // block-reduce BN partial sums; alias xs as scratch (tiles are done)
  __syncthreads();
  float* red = &xs[0][0];
  *(float4*)(red + pg * DF + f0) = s1;
  *(float4*)(red + 1024 + pg * DF + f0) = s2;
  __syncthreads();
  if (tid < DF) {
    float a = 0.f, b = 0.f;
#pragma unroll
    for (int g = 0; g < 16; ++g) {
      a += red[g * DF + tid];
      b += red[1024 + g * DF + tid];
    }
    atomicAdd(sums + tid, a);
    atomicAdd(sums + DF + tid, b);
  }
}

__global__ void finalize_kernel(const float* __restrict__ sums,
                                const float* __restrict__ gamma,
                                const float* __restrict__ beta,
                                float* __restrict__ scale,
                                float* __restrict__ shift) {
  int d = threadIdx.x;
  float mean = sums[d] * (1.0f / NPTS);
  float var = sums[DF + d] * (1.0f / NPTS) - mean * mean;
  float s = gamma[d] * rsqrtf(var + BN_EPS);
  scale[d] = s;
  shift[d] = fmaf(-mean, s, beta[d]);
}

// out = relu(out*scale + shift), pure streaming, in place.
#define BNBLK 2048
__global__ void bnrelu_kernel(float* __restrict__ out,
                              const float* __restrict__ scale,
                              const float* __restrict__ shift) {
  const int g = blockIdx.x * TPB + threadIdx.x;  // 524288 threads
  const int c = g & 15;                          // column float4-chunk
  const float4 sc = *(const float4*)(scale + c * 4);
  const float4 sh = *(const float4*)(shift + c * 4);
  const int rstride = (BNBLK * TPB) >> 4;        // 32768 rows per step
  for (int r = g >> 4; r < NPTS; r += rstride) {
    float4* p = (float4*)(out + (size_t)r * DF) + c;
    float4 h = *p;
    h.x = fmaxf(fmaf(h.x, sc.x, sh.x), 0.f);
    h.y = fmaxf(fmaf(h.y, sc.y, sh.y), 0.f);
    h.z = fmaxf(fmaf(h.z, sc.z, sh.z), 0.f);
    h.w = fmaxf(fmaf(h.w, sc.w, sh.w), 0.f);
    *p = h;
  }
}

extern "C" void kernel_launch(void* const* d_in, const int* in_sizes, int n_in,
                              void* d_out, int out_size, void* d_ws,
                              size_t ws_size, hipStream_t stream) {
  const float* x = (const float*)d_in[1];
  const int* cluster = (const int*)d_in[2];
  const float* Wv = (const float*)d_in[3];
  const float* bv = (const float*)d_in[4];
  const float* Wk = (const float*)d_in[5];
  const float* bk = (const float*)d_in[6];
  const float* Wq = (const float*)d_in[7];
  const float* bq = (const float*)d_in[8];
  const float* gamma = (const float*)d_in[9];
  const float* beta = (const float*)d_in[10];
  float* out = (float*)d_out;

  float* ws = (float*)d_ws;
  unsigned* q_u = (unsigned*)ws;
  unsigned* mmax_u = (unsigned*)(ws + 640000);
  float* denom = ws + 650000;
  float* sums = ws + 660000;
  float* scale = ws + 660128;
  float* shift = ws + 660192;
  float* Mv = ws + 660256;

  // zero q_u / mmax_u / denom / sums (0u == sortable "-inf" sentinel)
  hipMemsetAsync(d_ws, 0, 660256 * sizeof(float), stream);

  // 1) fused Q+K: q_u segment-max + k rows staged in d_out
  qk_kernel<<<QKBLK, TPB, 0, stream>>>(x, cluster, Wq, bq, Wk, bk, q_u, out);
  // 2) M = q[c].k, mmax segment-max
  mdot_kernel<<<(NPTS + 63) / 64, TPB, 0, stream>>>(out, cluster, q_u, Mv,
                                                    mmax_u);
  // 3) softmax denominators
  denom_kernel<<<(NPTS + 255) / 256, 256, 0, stream>>>(Mv, cluster, mmax_u,
                                                       denom);
  // 4) V projection + attn weighting + BN stats, raw h -> out
  v_kernel<<<VBLK, TPB, 0, stream>>>(x, cluster, Wv, bv, mmax_u, denom, Mv,
                                     sums, out);
  // 5) BN scale/shift
  finalize_kernel<<<1, 64, 0, stream>>>(sums, gamma, beta, scale, shift);
  // 6) streaming bn+relu in place
  bnrelu_kernel<<<BNBLK, TPB, 0, stream>>>(out, scale, shift);
}

// Round 7
// 558.154 us; speedup vs baseline: 3.0347x; 1.0428x over previous
//
#include <hip/hip_runtime.h>
#include <cstddef>

#define NPTS 500000
#define DF 64
#define NC 10000
#define BN_EPS 1e-5f

#define TPB 256
#define PTILE 64
#define NTILES ((NPTS + PTILE - 1) / PTILE)  // 7813
#define QVBLK 768                            // 3 blocks/CU (48 KB LDS)
#define SBLK 2048                            // streaming grids

// ---- order-preserving float<->uint encoding (for atomic max on floats) ----
__device__ __forceinline__ unsigned f2o(float f) {
  unsigned u = __float_as_uint(f);
  return (u & 0x80000000u) ? ~u : (u | 0x80000000u);
}
__device__ __forceinline__ float o2f(unsigned u) {
  return __uint_as_float((u & 0x80000000u) ? (u ^ 0x80000000u) : ~u);
}

// async global->LDS, 16B per lane. LDS dest is wave-uniform base + lane*16.
__device__ __forceinline__ void gload16(const float* g, float* l) {
  __builtin_amdgcn_global_load_lds(
      (const __attribute__((address_space(1))) void*)g,
      (__attribute__((address_space(3))) void*)l, 16, 0, 0);
}

// Stage one 64-point x tile (16 KB) into a linear LDS buffer via
// global_load_lds_dwordx4. PRE-SWIZZLED source: LDS 16B-slot (p, jb) receives
// x[p][(jb ^ (p>>2))*4 ..]; compute-side reads chunk j4 of row p at slot
// j4 ^ (p>>2) -> conflict-free, dest stays linear (rule 21).
__device__ __forceinline__ void stage_tile(float* xsbuf, const float* x,
                                           int pbase, int wave, int lane) {
#pragma unroll
  for (int i = 0; i < 4; ++i) {
    const int chunk = wave * 4 + i;       // 0..15, wave-uniform
    const int slot = chunk * 64 + lane;   // 16B slot id 0..1023
    const int p = slot >> 4;              // local point 0..63
    const int jb = slot & 15;             // 16B column block
    int gp = pbase + p;
    if (gp >= NPTS) gp = NPTS - 1;        // tail: safe garbage row
    const int jsrc = jb ^ (p >> 2);
    gload16(x + (size_t)gp * DF + jsrc * 4, xsbuf + chunk * 256);
  }
}

// ws layout (float/uint units):
// 0        : q_u     [NC*DF]   sortable-uint segment max of Q projections
// 640000   : mmax_u  [NC]      sortable-uint segment max of M
// 650000   : denom   [NC]      segment sum of exp
// 660000   : sums    [2*DF]    [sum h | sum h^2]
// 660128   : scale   [DF]
// 660192   : shift   [DF]
// 660256   : Mv      [NPTS]
// 1160256  : gtab    [NC*DF]   g_c = Wk^T q_c  (g-trick: M = x.g[c] + b[c])
// 1800256  : bdot    [NC]      b_c = bk . q_c
// raw v rows live in d_out until the apply pass overwrites them with result.

// ---------------------------------------------------------------------------
// Fused Q+V projection (round-3-proven dual-GEMM structure): one x staging,
// two GEMMs. Q -> read-filtered atomicMax into q_u ; V -> rows to vout(=out).
// Thread (fg=tid&15, pg=tid>>4) owns features f0..f0+3 of points pg*4..+3.
// ---------------------------------------------------------------------------
__launch_bounds__(TPB, 3)
__global__ void qv_kernel(const float* __restrict__ x,
                          const int* __restrict__ cluster,
                          const float* __restrict__ Wq,
                          const float* __restrict__ bq,
                          const float* __restrict__ Wv,
                          const float* __restrict__ bv,
                          unsigned* __restrict__ q_u,
                          float* __restrict__ vout) {
  __shared__ float Wt2[DF * 128];  // Wt2[j][f] : Q at f, V at f+64 (32 KB)
  __shared__ float xs[PTILE * DF]; // single-buffered x tile (16 KB)

  const int tid = threadIdx.x;
  const int lane = tid & 63;
  const int wave = tid >> 6;
  const int fg = tid & 15;
  const int pg = tid >> 4;
  const int f0 = fg * 4;

  // ---- stage both W's transposed (once per block) ----
  {
    const int f = tid & 63;
    const int jb = (tid >> 6) * 16;
#pragma unroll
    for (int i = 0; i < 4; ++i) {
      float4 a = *(const float4*)(Wq + f * DF + jb + i * 4);
      Wt2[(jb + i * 4 + 0) * 128 + f] = a.x;
      Wt2[(jb + i * 4 + 1) * 128 + f] = a.y;
      Wt2[(jb + i * 4 + 2) * 128 + f] = a.z;
      Wt2[(jb + i * 4 + 3) * 128 + f] = a.w;
      float4 b = *(const float4*)(Wv + f * DF + jb + i * 4);
      Wt2[(jb + i * 4 + 0) * 128 + 64 + f] = b.x;
      Wt2[(jb + i * 4 + 1) * 128 + 64 + f] = b.y;
      Wt2[(jb + i * 4 + 2) * 128 + 64 + f] = b.z;
      Wt2[(jb + i * 4 + 3) * 128 + 64 + f] = b.w;
    }
  }
  const float4 bq4 = *(const float4*)(bq + f0);
  const float4 bv4 = *(const float4*)(bv + f0);

  for (int t = blockIdx.x; t < NTILES; t += QVBLK) {
    const int pbase = t * PTILE;
    __syncthreads();  // previous tile's readers done (covers Wt2 on iter 0)
    stage_tile(xs, x, pbase, wave, lane);
    // cluster ids for this thread's 4 points
    int4 c4;
    {
      const int cb = pbase + pg * 4;
      if (cb + 3 < NPTS) {
        c4 = *(const int4*)(cluster + cb);
      } else {
        c4.x = cluster[cb + 0 < NPTS ? cb + 0 : NPTS - 1];
        c4.y = cluster[cb + 1 < NPTS ? cb + 1 : NPTS - 1];
        c4.z = cluster[cb + 2 < NPTS ? cb + 2 : NPTS - 1];
        c4.w = cluster[cb + 3 < NPTS ? cb + 3 : NPTS - 1];
      }
    }
    asm volatile("s_waitcnt vmcnt(0) lgkmcnt(0)" ::: "memory");
    __syncthreads();

    // ---- dual GEMM ----
    float4 accQ[4], accV[4];
#pragma unroll
    for (int pp = 0; pp < 4; ++pp) { accQ[pp] = bq4; accV[pp] = bv4; }
#pragma unroll 4
    for (int j4 = 0; j4 < 16; ++j4) {
      float4 wq[4], wv[4];
#pragma unroll
      for (int e = 0; e < 4; ++e) {
        wq[e] = *(const float4*)(Wt2 + (j4 * 4 + e) * 128 + f0);
        wv[e] = *(const float4*)(Wt2 + (j4 * 4 + e) * 128 + 64 + f0);
      }
      const int xoff = (j4 ^ pg) * 4;
#pragma unroll
      for (int pp = 0; pp < 4; ++pp) {
        float4 xv = *(const float4*)(xs + (pg * 4 + pp) * DF + xoff);
        accQ[pp].x = fmaf(xv.x, wq[0].x, accQ[pp].x);
        accQ[pp].y = fmaf(xv.x, wq[0].y, accQ[pp].y);
        accQ[pp].z = fmaf(xv.x, wq[0].z, accQ[pp].z);
        accQ[pp].w = fmaf(xv.x, wq[0].w, accQ[pp].w);
        accQ[pp].x = fmaf(xv.y, wq[1].x, accQ[pp].x);
        accQ[pp].y = fmaf(xv.y, wq[1].y, accQ[pp].y);
        accQ[pp].z = fmaf(xv.y, wq[1].z, accQ[pp].z);
        accQ[pp].w = fmaf(xv.y, wq[1].w, accQ[pp].w);
        accQ[pp].x = fmaf(xv.z, wq[2].x, accQ[pp].x);
        accQ[pp].y = fmaf(xv.z, wq[2].y, accQ[pp].y);
        accQ[pp].z = fmaf(xv.z, wq[2].z, accQ[pp].z);
        accQ[pp].w = fmaf(xv.z, wq[2].w, accQ[pp].w);
        accQ[pp].x = fmaf(xv.w, wq[3].x, accQ[pp].x);
        accQ[pp].y = fmaf(xv.w, wq[3].y, accQ[pp].y);
        accQ[pp].z = fmaf(xv.w, wq[3].z, accQ[pp].z);
        accQ[pp].w = fmaf(xv.w, wq[3].w, accQ[pp].w);
        accV[pp].x = fmaf(xv.x, wv[0].x, accV[pp].x);
        accV[pp].y = fmaf(xv.x, wv[0].y, accV[pp].y);
        accV[pp].z = fmaf(xv.x, wv[0].z, accV[pp].z);
        accV[pp].w = fmaf(xv.x, wv[0].w, accV[pp].w);
        accV[pp].x = fmaf(xv.y, wv[1].x, accV[pp].x);
        accV[pp].y = fmaf(xv.y, wv[1].y, accV[pp].y);
        accV[pp].z = fmaf(xv.y, wv[1].z, accV[pp].z);
        accV[pp].w = fmaf(xv.y, wv[1].w, accV[pp].w);
        accV[pp].x = fmaf(xv.z, wv[2].x, accV[pp].x);
        accV[pp].y = fmaf(xv.z, wv[2].y, accV[pp].y);
        accV[pp].z = fmaf(xv.z, wv[2].z, accV[pp].z);
        accV[pp].w = fmaf(xv.z, wv[2].w, accV[pp].w);
        accV[pp].x = fmaf(xv.w, wv[3].x, accV[pp].x);
        accV[pp].y = fmaf(xv.w, wv[3].y, accV[pp].y);
        accV[pp].z = fmaf(xv.w, wv[3].z, accV[pp].z);
        accV[pp].w = fmaf(xv.w, wv[3].w, accV[pp].w);
      }
    }

    // ---- epilogue: Q segment-max + raw V row store ----
#pragma unroll
    for (int pp = 0; pp < 4; ++pp) {
      const int p = pbase + pg * 4 + pp;
      if (p < NPTS) {
        const int cc = (pp == 0) ? c4.x : (pp == 1) ? c4.y
                       : (pp == 2) ? c4.z : c4.w;
        unsigned* dst = q_u + (size_t)cc * DF + f0;
        // monotone q_u: stale read only under-reports -> filter is race-safe
        const uint4 curq = *(const uint4*)dst;
        const unsigned ex = f2o(accQ[pp].x);
        const unsigned ey = f2o(accQ[pp].y);
        const unsigned ez = f2o(accQ[pp].z);
        const unsigned ew = f2o(accQ[pp].w);
        if (ex > curq.x) atomicMax(dst + 0, ex);
        if (ey > curq.y) atomicMax(dst + 1, ey);
        if (ez > curq.z) atomicMax(dst + 2, ez);
        if (ew > curq.w) atomicMax(dst + 3, ew);
        *(float4*)(vout + (size_t)p * DF + f0) = accV[pp];
      }
    }
  }
}

// ---------------------------------------------------------------------------
// g-trick precompute: per cluster c, g_c = Wk^T q_c, b_c = bk . q_c.
// Then M_p = x_p . g_{c_p} + b_{c_p} (exact reassociation of q.(Wk x + bk)).
// One wave per cluster; lane j owns output feature j.
// ---------------------------------------------------------------------------
__global__ void g_kernel(const unsigned* __restrict__ q_u,
                         const float* __restrict__ Wk,
                         const float* __restrict__ bk,
                         float* __restrict__ gtab,
                         float* __restrict__ bdot) {
  const int lane = threadIdx.x & 63;
  const int wave = threadIdx.x >> 6;
  const int c = blockIdx.x * 4 + wave;
  if (c >= NC) return;
  const unsigned* qp = q_u + (size_t)c * DF;
  float acc = 0.f, bacc = 0.f;
#pragma unroll 8
  for (int f = 0; f < DF; ++f) {
    const float qf = o2f(qp[f]);             // broadcast within wave
    acc = fmaf(qf, Wk[f * DF + lane], acc);  // coalesced across lanes
    bacc = fmaf(qf, bk[f], bacc);            // redundant per lane (cheap)
  }
  gtab[(size_t)c * DF + lane] = acc;
  if (lane == 0) bdot[c] = bacc;
}

// ---------------------------------------------------------------------------
// M_p = x_p . g[c_p] + b[c_p] ; Mv[p] = M ; filtered atomicMax into mmax_u.
// Streaming x (coalesced); g gather is L2/L3-resident (2.5 MB table).
// ---------------------------------------------------------------------------
__global__ void mdot_kernel(const float* __restrict__ x,
                            const int* __restrict__ cluster,
                            const float* __restrict__ gtab,
                            const float* __restrict__ bdot,
                            float* __restrict__ Mv,
                            unsigned* __restrict__ mmax_u) {
  const int tid = threadIdx.x;
  const int fg = tid & 15;
  const int pg = tid >> 4;
  const int f0 = fg * 4;
  for (int t = blockIdx.x; t < NTILES; t += gridDim.x) {
    const int pbase = t * PTILE;
#pragma unroll
    for (int pp = 0; pp < 4; ++pp) {
      const int p = pbase + pg * 4 + pp;
      float partial = 0.f;
      int cc = 0;
      if (p < NPTS) {
        cc = cluster[p];
        const float4 xv = *(const float4*)(x + (size_t)p * DF + f0);
        const float4 gv = *(const float4*)(gtab + (size_t)cc * DF + f0);
        partial = xv.x * gv.x + xv.y * gv.y + xv.z * gv.z + xv.w * gv.w;
      }
      partial += __shfl_xor(partial, 1, 64);
      partial += __shfl_xor(partial, 2, 64);
      partial += __shfl_xor(partial, 4, 64);
      partial += __shfl_xor(partial, 8, 64);
      if (fg == 0 && p < NPTS) {
        const float M = partial + bdot[cc];
        Mv[p] = M;
        const unsigned e = f2o(M);
        unsigned* mm = mmax_u + cc;
        if (e > *mm) atomicMax(mm, e);
      }
    }
  }
}

__global__ void denom_kernel(const float* __restrict__ Mv,
                             const int* __restrict__ cluster,
                             const unsigned* __restrict__ mmax_u,
                             float* __restrict__ denom) {
  int i = blockIdx.x * blockDim.x + threadIdx.x;
  if (i < NPTS) {
    int c = cluster[i];
    atomicAdd(denom + c, __expf(Mv[i] - o2f(mmax_u[c])));
  }
}

// ---------------------------------------------------------------------------
// BN statistics: stream raw v rows (in d_out), recompute attn, accumulate
// sum(h), sum(h^2) per feature. Read-only over v; no h materialization.
// ---------------------------------------------------------------------------
__launch_bounds__(TPB)
__global__ void stats_kernel(const float* __restrict__ v,
                             const int* __restrict__ cluster,
                             const unsigned* __restrict__ mmax_u,
                             const float* __restrict__ denom,
                             const float* __restrict__ Mv,
                             float* __restrict__ sums) {
  __shared__ float red[2048];
  const int tid = threadIdx.x;
  const int fg = tid & 15;
  const int pg = tid >> 4;
  const int f0 = fg * 4;
  float4 s1 = make_float4(0.f, 0.f, 0.f, 0.f);
  float4 s2 = make_float4(0.f, 0.f, 0.f, 0.f);
  for (int t = blockIdx.x; t < NTILES; t += gridDim.x) {
    const int pbase = t * PTILE;
#pragma unroll
    for (int pp = 0; pp < 4; ++pp) {
      const int p = pbase + pg * 4 + pp;
      if (p < NPTS) {
        const int cc = cluster[p];
        const float attn = __expf(Mv[p] - o2f(mmax_u[cc])) / denom[cc];
        const float4 vv = *(const float4*)(v + (size_t)p * DF + f0);
        const float hx = attn * vv.x, hy = attn * vv.y;
        const float hz = attn * vv.z, hw = attn * vv.w;
        s1.x += hx; s1.y += hy; s1.z += hz; s1.w += hw;
        s2.x += hx * hx; s2.y += hy * hy; s2.z += hz * hz; s2.w += hw * hw;
      }
    }
  }
  *(float4*)(red + pg * DF + f0) = s1;
  *(float4*)(red + 1024 + pg * DF + f0) = s2;
  __syncthreads();
  if (tid < DF) {
    float a = 0.f, b = 0.f;
#pragma unroll
    for (int g = 0; g < 16; ++g) {
      a += red[g * DF + tid];
      b += red[1024 + g * DF + tid];
    }
    atomicAdd(sums + tid, a);
    atomicAdd(sums + DF + tid, b);
  }
}

__global__ void finalize_kernel(const float* __restrict__ sums,
                                const float* __restrict__ gamma,
                                const float* __restrict__ beta,
                                float* __restrict__ scale,
                                float* __restrict__ shift) {
  int d = threadIdx.x;
  float mean = sums[d] * (1.0f / NPTS);
  float var = sums[DF + d] * (1.0f / NPTS) - mean * mean;
  float s = gamma[d] * rsqrtf(var + BN_EPS);
  scale[d] = s;
  shift[d] = fmaf(-mean, s, beta[d]);
}

// ---------------------------------------------------------------------------
// Apply: out = relu((attn*v)*scale + shift), in place over the raw v rows.
// One float4 per thread per step; column chunk constant across stride.
// ---------------------------------------------------------------------------
__global__ void apply_kernel(float* __restrict__ out,
                             const int* __restrict__ cluster,
                             const unsigned* __restrict__ mmax_u,
                             const float* __restrict__ denom,
                             const float* __restrict__ Mv,
                             const float* __restrict__ scale,
                             const float* __restrict__ shift) {
  const int g0 = blockIdx.x * TPB + threadIdx.x;
  const int c = g0 & 15;  // column float4-chunk (stride preserves it)
  const float4 sc = *(const float4*)(scale + c * 4);
  const float4 sh = *(const float4*)(shift + c * 4);
  const int stride = SBLK * TPB;
  for (int idx = g0; idx < NPTS * 16; idx += stride) {
    const int r = idx >> 4;
    const int cc = cluster[r];
    const float attn = __expf(Mv[r] - o2f(mmax_u[cc])) / denom[cc];
    float4* p = (float4*)out + idx;
    float4 v = *p;
    v.x = fmaxf(fmaf(attn * v.x, sc.x, sh.x), 0.f);
    v.y = fmaxf(fmaf(attn * v.y, sc.y, sh.y), 0.f);
    v.z = fmaxf(fmaf(attn * v.z, sc.z, sh.z), 0.f);
    v.w = fmaxf(fmaf(attn * v.w, sc.w, sh.w), 0.f);
    *p = v;
  }
}

extern "C" void kernel_launch(void* const* d_in, const int* in_sizes, int n_in,
                              void* d_out, int out_size, void* d_ws,
                              size_t ws_size, hipStream_t stream) {
  const float* x = (const float*)d_in[1];
  const int* cluster = (const int*)d_in[2];
  const float* Wv = (const float*)d_in[3];
  const float* bv = (const float*)d_in[4];
  const float* Wk = (const float*)d_in[5];
  const float* bk = (const float*)d_in[6];
  const float* Wq = (const float*)d_in[7];
  const float* bq = (const float*)d_in[8];
  const float* gamma = (const float*)d_in[9];
  const float* beta = (const float*)d_in[10];
  float* out = (float*)d_out;

  float* ws = (float*)d_ws;
  unsigned* q_u = (unsigned*)ws;
  unsigned* mmax_u = (unsigned*)(ws + 640000);
  float* denom = ws + 650000;
  float* sums = ws + 660000;
  float* scale = ws + 660128;
  float* shift = ws + 660192;
  float* Mv = ws + 660256;
  float* gtab = ws + 1160256;   // [NC*DF]
  float* bdot = ws + 1800256;   // [NC]

  // zero q_u / mmax_u / denom / sums (0u == sortable "-inf" sentinel)
  hipMemsetAsync(d_ws, 0, 660256 * sizeof(float), stream);

  // 1) fused Q+V: q_u segment-max + raw v rows -> d_out
  qv_kernel<<<QVBLK, TPB, 0, stream>>>(x, cluster, Wq, bq, Wv, bv, q_u, out);
  // 2) per-cluster g = Wk^T q, b = bk.q  (k never materialized)
  g_kernel<<<(NC + 3) / 4, TPB, 0, stream>>>(q_u, Wk, bk, gtab, bdot);
  // 3) M = x.g[c] + b[c], mmax segment-max  (streaming x)
  mdot_kernel<<<SBLK, TPB, 0, stream>>>(x, cluster, gtab, bdot, Mv, mmax_u);
  // 4) softmax denominators
  denom_kernel<<<(NPTS + 255) / 256, 256, 0, stream>>>(Mv, cluster, mmax_u,
                                                       denom);
  // 5) BN stats over h = attn*v (streaming v)
  stats_kernel<<<SBLK, TPB, 0, stream>>>(out, cluster, mmax_u, denom, Mv,
                                         sums);
  // 6) BN scale/shift
  finalize_kernel<<<1, 64, 0, stream>>>(sums, gamma, beta, scale, shift);
  // 7) apply attn + bn + relu in place
  apply_kernel<<<SBLK, TPB, 0, stream>>>(out, cluster, mmax_u, denom, Mv,
                                         scale, shift);
}